// Round 6
// baseline (298.652 us; speedup 1.0000x reference)
//
#include <hip/hip_runtime.h>

// KANN_4578435137547: quadratic Lagrange FEM basis + weight contraction.
// Column-major single-pass writer: each thread owns ONE column, iterates rows.
// Per-row-group state ({nl, x_t} table in d_ws) is wave-uniform -> scalar
// loads; value select is 3 branch-free cndmasks reused across 8 rows; the
// store stream has no divides/branches/vector-loads. One pass, every output
// byte written exactly once.
// Outputs (flat f32): t[32768], dt[32768], ddt[32768],
//   phi/dphi/ddphi each [32768][2049].

#define KN_NODES    2049
#define KN_SAMPLES  4096
#define KN_IK       (KN_SAMPLES * 8)                   // 32768
#define KN_HEAD     (3 * KN_IK)                        // 98304
#define KN_PHI_LEN  ((size_t)KN_IK * KN_NODES)         // 67,141,632

// Head contractions + {nl, x_t} table. 32768 threads.
__global__ __launch_bounds__(256)
void KANN_pre(const float* __restrict__ x, const float* __restrict__ w,
              float* __restrict__ out, int2* __restrict__ tbl) {
    int ik = blockIdx.x * 256 + threadIdx.x;
    if (ik >= KN_IK) return;
    int i = ik >> 3, k = ik & 7;
    float xv  = x[i];
    float xs  = 2048.0f * xv;
    float fid = floorf(0.5f * xs);
    fid = fminf(fmaxf(fid, 0.0f), 1023.0f);
    int   nl  = 2 * (int)fid;                 // even, [0, 2046]
    float x_t = xs - (float)nl - 1.0f;        // [-1, 1]
    if (k == 0) tbl[i] = make_int2(nl, __float_as_int(x_t));

    const float* wk = w + k * KN_NODES + nl;
    float w0 = wk[0], w1 = wk[1], w2 = wk[2];
    float p0 = 0.5f * x_t * (x_t - 1.0f);
    float p1 = 1.0f - x_t * x_t;
    float p2 = 0.5f * x_t * (x_t + 1.0f);
    out[ik]             = w0 * p0 + w1 * p1 + w2 * p2;
    out[KN_IK + ik]     = (w0 * (x_t - 0.5f) - 2.0f * w1 * x_t + w2 * (x_t + 0.5f)) * 2048.0f;
    out[2 * KN_IK + ik] = (w0 - 2.0f * w1 + w2) * 4194304.0f;
}

// Column-major writer. grid (9, 256, 3) x 256 threads.
// Thread -> column c = blockIdx.x*256+tid (c<2049 valid); rows rbase..rbase+127.
__global__ __launch_bounds__(256)
void KANN_fill(const int2* __restrict__ tbl, float* __restrict__ out) {
    const int c     = blockIdx.x * 256 + threadIdx.x;
    const int plane = blockIdx.z;                 // 0=phi, 1=dphi, 2=ddphi
    const int rbase = blockIdx.y * 128;
    const bool cv   = (c < KN_NODES);

    float* base = out + KN_HEAD + (size_t)plane * KN_PHI_LEN
                + (size_t)rbase * KN_NODES + c;

#pragma unroll
    for (int r8 = 0; r8 < 16; ++r8) {
        // Sample index for this 8-row group: wave-uniform -> scalar load.
        int2 e   = tbl[blockIdx.y * 16 + r8];
        int   nl = e.x;
        float xt = __int_as_float(e.y);

        float b0, b1, b2;
        if (plane == 0)      { b0 = 0.5f * xt * (xt - 1.0f); b1 = 1.0f - xt * xt; b2 = 0.5f * xt * (xt + 1.0f); }
        else if (plane == 1) { b0 = (xt - 0.5f) * 2048.0f; b1 = -4096.0f * xt; b2 = (xt + 0.5f) * 2048.0f; }
        else                 { b0 = 4194304.0f; b1 = -8388608.0f; b2 = 4194304.0f; }

        int   d = c - nl;
        float v = (d == 0) ? b0 : ((d == 1) ? b1 : ((d == 2) ? b2 : 0.0f));

        if (cv) {
            float* p = base + (size_t)(r8 * 8) * KN_NODES;
#pragma unroll
            for (int j = 0; j < 8; ++j)
                p[(size_t)j * KN_NODES] = v;      // 256B contiguous per wave-inst
        }
    }
}

extern "C" void kernel_launch(void* const* d_in, const int* in_sizes, int n_in,
                              void* d_out, int out_size, void* d_ws, size_t ws_size,
                              hipStream_t stream) {
    const float* x = (const float*)d_in[0];
    const float* w = (const float*)d_in[1];
    float* out = (float*)d_out;
    int2* tbl = (int2*)d_ws;                      // 32 KB scratch

    KANN_pre<<<dim3(KN_IK / 256), dim3(256), 0, stream>>>(x, w, out, tbl);
    KANN_fill<<<dim3(9, 256, 3), dim3(256), 0, stream>>>(tbl, out);
}

// Round 7
// 152.434 us; speedup vs baseline: 1.9592x; 1.9592x over previous
//
#include <hip/hip_runtime.h>

// KANN_4578435137547: quadratic Lagrange FEM basis + weight contraction.
// Structure (best measured): hipMemsetAsync zeroes all 806 MB at the fill
// path's ~6.7 TB/s (no hand-written writer exceeded 5.1 — R1/R2/R3/R5),
// then ONE fused scatter kernel writes all nonzeros: per (i,k) thread,
// 3 coalesced head floats + 3 plane windows of 3 floats (dwordx3).
// Outputs (flat f32): t[32768], dt[32768], ddt[32768],
//   phi/dphi/ddphi each [32768][2049].

#define KN_NODES    2049
#define KN_IK       32768                               // 4096 samples * 8 width
#define KN_HEAD     (3 * KN_IK)                         // 98304
#define KN_PHI_LEN  ((size_t)KN_IK * KN_NODES)          // 67,141,632

__global__ __launch_bounds__(256)
void KANN_scatter(const float* __restrict__ x, const float* __restrict__ w,
                  float* __restrict__ out) {
    int ik = blockIdx.x * 256 + threadIdx.x;
    if (ik >= KN_IK) return;
    int i = ik >> 3, k = ik & 7;

    float xv  = x[i];
    float xs  = 2048.0f * xv;
    float fid = floorf(0.5f * xs);
    fid = fminf(fmaxf(fid, 0.0f), 1023.0f);
    int   nl  = 2 * (int)fid;                 // even, [0, 2046]
    float x_t = xs - (float)nl - 1.0f;        // [-1, 1]

    // Basis values for all three planes.
    float p0 = 0.5f * x_t * (x_t - 1.0f);
    float p1 = 1.0f - x_t * x_t;
    float p2 = 0.5f * x_t * (x_t + 1.0f);
    float d0 = (x_t - 0.5f) * 2048.0f;
    float d1 = -4096.0f * x_t;
    float d2 = (x_t + 0.5f) * 2048.0f;
    const float s0 = 4194304.0f, s1 = -8388608.0f;

    // Head contractions (coalesced across ik).
    const float* wk = w + k * KN_NODES + nl;
    float w0 = wk[0], w1 = wk[1], w2 = wk[2];
    out[ik]             = w0 * p0 + w1 * p1 + w2 * p2;
    out[KN_IK + ik]     = w0 * d0 + w1 * d1 + w2 * d2;
    out[2 * KN_IK + ik] = (w0 - 2.0f * w1 + w2) * 4194304.0f;

    // Window scatter: 3 floats per plane at row ik, col nl (merged dwordx3).
    float* pphi = out + KN_HEAD + (size_t)ik * KN_NODES + nl;
    pphi[0] = p0; pphi[1] = p1; pphi[2] = p2;
    float* pd = pphi + KN_PHI_LEN;
    pd[0] = d0; pd[1] = d1; pd[2] = d2;
    float* ps = pd + KN_PHI_LEN;
    ps[0] = s0; ps[1] = s1; ps[2] = s0;
}

extern "C" void kernel_launch(void* const* d_in, const int* in_sizes, int n_in,
                              void* d_out, int out_size, void* d_ws, size_t ws_size,
                              hipStream_t stream) {
    const float* x = (const float*)d_in[0];
    const float* w = (const float*)d_in[1];
    float* out = (float*)d_out;

    hipMemsetAsync(out, 0, (size_t)out_size * sizeof(float), stream);
    KANN_scatter<<<dim3(KN_IK / 256), dim3(256), 0, stream>>>(x, w, out);
}